// Round 2
// baseline (325.363 us; speedup 1.0000x reference)
//
#include <hip/hip_runtime.h>

// 2D DWT (db2, symmetric pad, pywt-compatible), barrier-free / LDS-free, v2.
// x: (16,3,1024,1024) f32 -> cA, cH: (16,3,513,513) f32, concatenated in d_out.
//
// Changes vs v1 (neutral at 316us):
//  - TI 8 -> 16: strip-overlap read amplification 1.125 -> 1.0625,
//    prologue loads halved. Grid 3120 -> 1584 blocks (6.2/CU, 3.1 waves/SIMD).
//  - 2-deep prefetch: three live row-pair sets (a,b,c); loads issued 2
//    iterations before use (~2x latency tolerance vs v1's 1-deep).
//  - Tail prefetch guarded (ii+2 < nrows): v1 wasted 2 row loads/block.
//  - Nontemporal stores: output is never re-read; keep L2/L3 for the
//    strip-overlap input reads.
//  - XCD-chunked block swizzle (1584 % 8 == 0): neighboring strips that
//    share 2 input rows land on the same XCD's L2.

#define N 1024
#define NOUT 513
#define TI 16                            // output rows per block
#define STRIPS ((NOUT + TI - 1) / TI)    // 33
#define NIMG 48
#define NBLK (STRIPS * NIMG)             // 1584 (divisible by 8)

__device__ __forceinline__ int refl(int p) {
    int r = p - 2;
    r = (r < 0) ? (-1 - r) : r;
    r = (r > N - 1) ? (2 * N - 1 - r) : r;
    return r;
}

__device__ __forceinline__ float4 comb4(float w0, const float4 a, float w1, const float4 b,
                                        float w2, const float4 c, float w3, const float4 d) {
    float4 r;
    r.x = fmaf(w0, a.x, fmaf(w1, b.x, fmaf(w2, c.x, w3 * d.x)));
    r.y = fmaf(w0, a.y, fmaf(w1, b.y, fmaf(w2, c.y, w3 * d.y)));
    r.z = fmaf(w0, a.z, fmaf(w1, b.z, fmaf(w2, c.z, w3 * d.z)));
    r.w = fmaf(w0, a.w, fmaf(w1, b.w, fmaf(w2, c.w, w3 * d.w)));
    return r;
}

__device__ __forceinline__ float2 comb2(float w0, const float2 a, float w1, const float2 b,
                                        float w2, const float2 c, float w3, const float2 d) {
    float2 r;
    r.x = fmaf(w0, a.x, fmaf(w1, b.x, fmaf(w2, c.x, w3 * d.x)));
    r.y = fmaf(w0, a.y, fmaf(w1, b.y, fmaf(w2, c.y, w3 * d.y)));
    return r;
}

__global__ __launch_bounds__(128, 4) void dwt2_deep(const float* __restrict__ x,
                                                    float* __restrict__ out) {
    // reversed filter taps (true convolution)
    const float l0 =  0.48296291314469025f;
    const float l1 =  0.836516303737469f;
    const float l2 =  0.22414386804185735f;
    const float l3 = -0.12940952255092145f;
    const float h0 = -0.12940952255092145f;
    const float h1 = -0.22414386804185735f;
    const float h2 =  0.836516303737469f;
    const float h3 = -0.48296291314469025f;

    // XCD-chunked swizzle: consecutive-resident wgs on one XCD get a
    // contiguous wg range -> neighbor strips share that XCD's L2.
    const int bid = blockIdx.x;
    const int wg  = (bid & 7) * (NBLK / 8) + (bid >> 3);
    const int img   = wg / STRIPS;
    const int strip = wg % STRIPS;

    const int i0 = strip * TI;
    const int u  = threadIdx.x;          // 0..127
    const int c  = 8 * u;                // owned columns c..c+7
    const int ce = (u == 0) ? 0 : (c - 2);  // left-neighbor cols (u=0: fixed up)

    const float* xim = x + (size_t)img * N * N;
    const size_t plane = (size_t)NOUT * NOUT;
    float* cA = out + (size_t)img * plane;
    float* cH = out + ((size_t)NIMG + img) * plane;

    const int nrows = (NOUT - i0 < TI) ? (NOUT - i0) : TI;

    // three live row-pair sets: a = xp[2i,2i+1], b = xp[2i+2,2i+3],
    // c = xp[2i+4,2i+5] (prefetched 2 iterations ahead).
    const float* p0 = xim + (size_t)refl(2 * i0)     * N;
    const float* p1 = xim + (size_t)refl(2 * i0 + 1) * N;
    const float* p2 = xim + (size_t)refl(2 * i0 + 2) * N;
    const float* p3 = xim + (size_t)refl(2 * i0 + 3) * N;
    const float* p4 = xim + (size_t)refl(2 * i0 + 4) * N;
    const float* p5 = xim + (size_t)refl(2 * i0 + 5) * N;

    float4 a0a = *reinterpret_cast<const float4*>(p0 + c);
    float4 a0b = *reinterpret_cast<const float4*>(p0 + c + 4);
    float2 a0e = *reinterpret_cast<const float2*>(p0 + ce);
    float4 a1a = *reinterpret_cast<const float4*>(p1 + c);
    float4 a1b = *reinterpret_cast<const float4*>(p1 + c + 4);
    float2 a1e = *reinterpret_cast<const float2*>(p1 + ce);
    float4 b0a = *reinterpret_cast<const float4*>(p2 + c);
    float4 b0b = *reinterpret_cast<const float4*>(p2 + c + 4);
    float2 b0e = *reinterpret_cast<const float2*>(p2 + ce);
    float4 b1a = *reinterpret_cast<const float4*>(p3 + c);
    float4 b1b = *reinterpret_cast<const float4*>(p3 + c + 4);
    float2 b1e = *reinterpret_cast<const float2*>(p3 + ce);
    float4 c0a = *reinterpret_cast<const float4*>(p4 + c);
    float4 c0b = *reinterpret_cast<const float4*>(p4 + c + 4);
    float2 c0e = *reinterpret_cast<const float2*>(p4 + ce);
    float4 c1a = *reinterpret_cast<const float4*>(p5 + c);
    float4 c1b = *reinterpret_cast<const float4*>(p5 + c + 4);
    float2 c1e = *reinterpret_cast<const float2*>(p5 + ce);

    for (int ii = 0; ii < nrows; ++ii) {
        const int i = i0 + ii;

        // ---- vertical transform: output row i from xp rows (a0,a1,b0,b1) ----
        float4 vloA = comb4(l0, a0a, l1, a1a, l2, b0a, l3, b1a);
        float4 vloB = comb4(l0, a0b, l1, a1b, l2, b0b, l3, b1b);
        float2 plo  = comb2(l0, a0e, l1, a1e, l2, b0e, l3, b1e);
        float4 vhiA = comb4(h0, a0a, h1, a1a, h2, b0a, h3, b1a);
        float4 vhiB = comb4(h0, a0b, h1, a1b, h2, b0b, h3, b1b);
        float2 phi  = comb2(h0, a0e, h1, a1e, h2, b0e, h3, b1e);

        // left image edge: j=0 uses xp cols (1,0,0,1)
        if (u == 0) {
            plo = make_float2(vloA.y, vloA.x);
            phi = make_float2(vhiA.y, vhiA.x);
        }

        // ---- rotate carries a<-b<-c, issue prefetch into c (used at ii+2) ----
        a0a = b0a; a0b = b0b; a0e = b0e;
        a1a = b1a; a1b = b1b; a1e = b1e;
        b0a = c0a; b0b = c0b; b0e = c0e;
        b1a = c1a; b1b = c1b; b1e = c1e;
        if (ii + 2 < nrows) {
            const float* q0 = xim + (size_t)refl(2 * i + 6) * N;
            const float* q1 = xim + (size_t)refl(2 * i + 7) * N;
            c0a = *reinterpret_cast<const float4*>(q0 + c);
            c0b = *reinterpret_cast<const float4*>(q0 + c + 4);
            c0e = *reinterpret_cast<const float2*>(q0 + ce);
            c1a = *reinterpret_cast<const float4*>(q1 + c);
            c1b = *reinterpret_cast<const float4*>(q1 + c + 4);
            c1e = *reinterpret_cast<const float2*>(q1 + ce);
        }

        // ---- horizontal transform (registers only) + nontemporal store ----
        float oA0 = fmaf(l0, plo.x,  fmaf(l1, plo.y,  fmaf(l2, vloA.x, l3 * vloA.y)));
        float oA1 = fmaf(l0, vloA.x, fmaf(l1, vloA.y, fmaf(l2, vloA.z, l3 * vloA.w)));
        float oA2 = fmaf(l0, vloA.z, fmaf(l1, vloA.w, fmaf(l2, vloB.x, l3 * vloB.y)));
        float oA3 = fmaf(l0, vloB.x, fmaf(l1, vloB.y, fmaf(l2, vloB.z, l3 * vloB.w)));
        float oH0 = fmaf(l0, phi.x,  fmaf(l1, phi.y,  fmaf(l2, vhiA.x, l3 * vhiA.y)));
        float oH1 = fmaf(l0, vhiA.x, fmaf(l1, vhiA.y, fmaf(l2, vhiA.z, l3 * vhiA.w)));
        float oH2 = fmaf(l0, vhiA.z, fmaf(l1, vhiA.w, fmaf(l2, vhiB.x, l3 * vhiB.y)));
        float oH3 = fmaf(l0, vhiB.x, fmaf(l1, vhiB.y, fmaf(l2, vhiB.z, l3 * vhiB.w)));

        float* pa = cA + (size_t)i * NOUT + 4 * u;
        float* ph = cH + (size_t)i * NOUT + 4 * u;
        __builtin_nontemporal_store(oA0, pa + 0);
        __builtin_nontemporal_store(oA1, pa + 1);
        __builtin_nontemporal_store(oA2, pa + 2);
        __builtin_nontemporal_store(oA3, pa + 3);
        __builtin_nontemporal_store(oH0, ph + 0);
        __builtin_nontemporal_store(oH1, ph + 1);
        __builtin_nontemporal_store(oH2, ph + 2);
        __builtin_nontemporal_store(oH3, ph + 3);

        // right image edge: j=512 uses xp cols (1022,1023,1023,1022)
        if (u == 127) {
            float eA = fmaf(l0, vloB.z, fmaf(l1, vloB.w, fmaf(l2, vloB.w, l3 * vloB.z)));
            float eH = fmaf(l0, vhiB.z, fmaf(l1, vhiB.w, fmaf(l2, vhiB.w, l3 * vhiB.z)));
            __builtin_nontemporal_store(eA, pa + 4);
            __builtin_nontemporal_store(eH, ph + 4);
        }
    }
}

extern "C" void kernel_launch(void* const* d_in, const int* in_sizes, int n_in,
                              void* d_out, int out_size, void* d_ws, size_t ws_size,
                              hipStream_t stream) {
    (void)in_sizes; (void)n_in; (void)d_ws; (void)ws_size; (void)out_size;
    const float* x = (const float*)d_in[0];
    float* out = (float*)d_out;
    dim3 grid(NBLK);      // 1584 blocks, XCD-swizzled in-kernel
    dim3 block(128);
    dwt2_deep<<<grid, block, 0, stream>>>(x, out);
}

// Round 3
// 310.745 us; speedup vs baseline: 1.0470x; 1.0470x over previous
//
#include <hip/hip_runtime.h>

// 2D DWT (db2, symmetric pad, pywt-compatible) v3: max-occupancy fused kernel.
// x: (16,3,1024,1024) f32 -> cA, cH: (16,3,513,513) f32, concatenated in d_out.
//
// Design (merging the best of rounds 0-2):
//  - 256 threads, 4 input cols/thread, TI=8 -> 3120 blocks (12.2/CU), and a
//    small register footprint (target <=64 VGPR => 8 waves/SIMD, 32 waves/CU).
//    Occupancy is the MLP lever (round 2 showed 9 waves/CU + deep prefetch
//    = 1.75 TB/s; 32 waves/CU x 1-deep gives ~3x the loads in flight).
//  - Barrier-free: vertical + horizontal both lane-local (2-col redundant
//    edge load, L1-hit). No __syncthreads anywhere.
//  - Dense aligned stores: wave-private LDS bounce (same-wave DS ops are
//    in-order; no barrier) turns per-thread output pairs (lane stride 8B)
//    into lane-dense dword stores (256B/inst, always 4B-aligned-dense).
//  - No nontemporal hints (v2 regression suspect: NT scattered dwords can't
//    merge in L2, and vmcnt waits drain them every iteration).

#define N 1024
#define NOUT 513
#define TI 8
#define STRIPS ((NOUT + TI - 1) / TI)   // 65
#define NIMG 48

__device__ __forceinline__ int refl(int p) {
    int r = p - 2;
    r = (r < 0) ? (-1 - r) : r;
    r = (r > N - 1) ? (2 * N - 1 - r) : r;
    return r;
}

__device__ __forceinline__ float4 comb4(float w0, const float4 a, float w1, const float4 b,
                                        float w2, const float4 c, float w3, const float4 d) {
    float4 r;
    r.x = fmaf(w0, a.x, fmaf(w1, b.x, fmaf(w2, c.x, w3 * d.x)));
    r.y = fmaf(w0, a.y, fmaf(w1, b.y, fmaf(w2, c.y, w3 * d.y)));
    r.z = fmaf(w0, a.z, fmaf(w1, b.z, fmaf(w2, c.z, w3 * d.z)));
    r.w = fmaf(w0, a.w, fmaf(w1, b.w, fmaf(w2, c.w, w3 * d.w)));
    return r;
}

__device__ __forceinline__ float2 comb2(float w0, const float2 a, float w1, const float2 b,
                                        float w2, const float2 c, float w3, const float2 d) {
    float2 r;
    r.x = fmaf(w0, a.x, fmaf(w1, b.x, fmaf(w2, c.x, w3 * d.x)));
    r.y = fmaf(w0, a.y, fmaf(w1, b.y, fmaf(w2, c.y, w3 * d.y)));
    return r;
}

__global__ __launch_bounds__(256, 8) void dwt2_v3(const float* __restrict__ x,
                                                  float* __restrict__ out) {
    // reversed filter taps (true convolution)
    const float l0 =  0.48296291314469025f;
    const float l1 =  0.836516303737469f;
    const float l2 =  0.22414386804185735f;
    const float l3 = -0.12940952255092145f;
    const float h0 = -0.12940952255092145f;
    const float h1 = -0.22414386804185735f;
    const float h2 =  0.836516303737469f;
    const float h3 = -0.48296291314469025f;

    __shared__ float sA[4][128];   // wave-private store-staging (2 KB)
    __shared__ float sH[4][128];   // 2 KB

    const int strip = blockIdx.x;
    const int img   = blockIdx.y;
    const int i0 = strip * TI;
    const int u    = threadIdx.x;        // 0..255
    const int wave = u >> 6;
    const int lane = u & 63;
    const int c4 = 4 * u;                // owned input cols c4..c4+3
    const int ce = (u == 0) ? 0 : (c4 - 2);  // left-neighbor cols (u=0: fixed up)

    const float* xim = x + (size_t)img * N * N;
    const size_t plane = (size_t)NOUT * NOUT;
    float* cA = out + (size_t)img * plane;
    float* cH = out + ((size_t)NIMG + img) * plane;

    const int nrows = (NOUT - i0 < TI) ? (NOUT - i0) : TI;

    // prologue: xp rows 2*i0 .. 2*i0+3 (pairs a, b)
    const float* p0 = xim + (size_t)refl(2 * i0)     * N;
    const float* p1 = xim + (size_t)refl(2 * i0 + 1) * N;
    const float* p2 = xim + (size_t)refl(2 * i0 + 2) * N;
    const float* p3 = xim + (size_t)refl(2 * i0 + 3) * N;

    float4 a0m = *reinterpret_cast<const float4*>(p0 + c4);
    float2 a0e = *reinterpret_cast<const float2*>(p0 + ce);
    float4 a1m = *reinterpret_cast<const float4*>(p1 + c4);
    float2 a1e = *reinterpret_cast<const float2*>(p1 + ce);
    float4 b0m = *reinterpret_cast<const float4*>(p2 + c4);
    float2 b0e = *reinterpret_cast<const float2*>(p2 + ce);
    float4 b1m = *reinterpret_cast<const float4*>(p3 + c4);
    float2 b1e = *reinterpret_cast<const float2*>(p3 + ce);

    for (int ii = 0; ii < nrows; ++ii) {
        const int i = i0 + ii;

        // ---- vertical transform: output row i from xp rows (a0,a1,b0,b1) ----
        float4 vloM = comb4(l0, a0m, l1, a1m, l2, b0m, l3, b1m);
        float2 vloE = comb2(l0, a0e, l1, a1e, l2, b0e, l3, b1e);
        float4 vhiM = comb4(h0, a0m, h1, a1m, h2, b0m, h3, b1m);
        float2 vhiE = comb2(h0, a0e, h1, a1e, h2, b0e, h3, b1e);

        // left image edge: j=0 uses xp cols (1,0,0,1)
        if (u == 0) {
            vloE = make_float2(vloM.y, vloM.x);
            vhiE = make_float2(vhiM.y, vhiM.x);
        }

        // ---- rotate carries a<-b, prefetch next row pair into b ----
        a0m = b0m; a0e = b0e;
        a1m = b1m; a1e = b1e;
        if (ii + 1 < nrows) {
            const float* q0 = xim + (size_t)refl(2 * i + 4) * N;
            const float* q1 = xim + (size_t)refl(2 * i + 5) * N;
            b0m = *reinterpret_cast<const float4*>(q0 + c4);
            b0e = *reinterpret_cast<const float2*>(q0 + ce);
            b1m = *reinterpret_cast<const float4*>(q1 + c4);
            b1e = *reinterpret_cast<const float2*>(q1 + ce);
        }

        // ---- horizontal transform: outputs j=2u (edge+main) and j=2u+1 ----
        float oA0 = fmaf(l0, vloE.x, fmaf(l1, vloE.y, fmaf(l2, vloM.x, l3 * vloM.y)));
        float oA1 = fmaf(l0, vloM.x, fmaf(l1, vloM.y, fmaf(l2, vloM.z, l3 * vloM.w)));
        float oH0 = fmaf(l0, vhiE.x, fmaf(l1, vhiE.y, fmaf(l2, vhiM.x, l3 * vhiM.y)));
        float oH1 = fmaf(l0, vhiM.x, fmaf(l1, vhiM.y, fmaf(l2, vhiM.z, l3 * vhiM.w)));

        // ---- wave-private LDS bounce -> lane-dense global stores ----
        sA[wave][2 * lane]     = oA0;
        sA[wave][2 * lane + 1] = oA1;
        sH[wave][2 * lane]     = oH0;
        sH[wave][2 * lane + 1] = oH1;
        // same-wave DS ordering; compiler inserts lgkmcnt before the reads
        float rA0 = sA[wave][lane];
        float rA1 = sA[wave][64 + lane];
        float rH0 = sH[wave][lane];
        float rH1 = sH[wave][64 + lane];

        const int j0 = (wave << 7) + lane;
        float* pa = cA + (size_t)i * NOUT;
        float* ph = cH + (size_t)i * NOUT;
        pa[j0]      = rA0;
        pa[j0 + 64] = rA1;
        ph[j0]      = rH0;
        ph[j0 + 64] = rH1;

        // right image edge: j=512 uses xp cols (1022,1023,1023,1022)
        if (u == 255) {
            pa[512] = fmaf(l0, vloM.z, fmaf(l1, vloM.w, fmaf(l2, vloM.w, l3 * vloM.z)));
            ph[512] = fmaf(l0, vhiM.z, fmaf(l1, vhiM.w, fmaf(l2, vhiM.w, l3 * vhiM.z)));
        }
    }
}

extern "C" void kernel_launch(void* const* d_in, const int* in_sizes, int n_in,
                              void* d_out, int out_size, void* d_ws, size_t ws_size,
                              hipStream_t stream) {
    (void)in_sizes; (void)n_in; (void)d_ws; (void)ws_size; (void)out_size;
    const float* x = (const float*)d_in[0];
    float* out = (float*)d_out;
    dim3 grid(STRIPS, NIMG);    // 65 x 48 = 3120 blocks
    dim3 block(256);
    dwt2_v3<<<grid, block, 0, stream>>>(x, out);
}